// Round 6
// baseline (133.942 us; speedup 1.0000x reference)
//
#include <hip/hip_runtime.h>

// ---------------------------------------------------------------------------
// DeepLagrangianNetwork head — round 10: all-MFMA, zero-LDS, zero-barrier.
// Rounds 0-9 showed: structure-invariant ~52-62 us, waves ~85% stalled on
// phase-1 SMEM chains + LDS h1 round-trip, lockstep waves can't hide it.
// This round deletes that structure:
//   layer 1 (K=4) done by MFMA with permuted W1 rows so that layer-1 C
//   output IS layer-2's B fragment (identity handoff, in registers).
//   Permutation: A-tile mt, C-row m holds W1 row
//       nu(mt,m) = 32*(mt>>1) + 8*(m>>2) + 4*(mt&1) + (m&3)
//   => lane (q,c) packs its 16 lrelu'd layer-1 outputs into exactly
//      B[k=8q+j][n=c] (ch q) and B[k=32+8q+j][n=c] (ch 4+q). Verified:
//      q=0: acc1[0][0..3],acc1[1][0..3] = neurons 0..7 = k 0..7, etc.
//   b1 rides the k=4 slot (A: b1, B: 1.0). Accuracy: W1,b1,x all hi/lo
//   bf16-split (3 MFMA/tile: hh + hi*lo + lo*hi, residual ~2^-18) so h1 is
//   fp32-exact before its usual bf16 rounding -> absmax must stay 0.0078125.
// Layer 2 + heads + epilogue unchanged from round 9 (verified path):
//   h2^T = W2 @ h1^T (MFMA, A=W2 tiles), heads on fp32 h2 in-register
//   (packed v_pk_fma_f32), quad-reduce via shfl_xor, H = L L^T + 1e-9 I.
// NO __shared__, NO __syncthreads, NO launch_bounds min-waves clause
// (it clamps to 64 VGPR and spills - confirmed rounds 6 & 8).
// Fragment layouts (m89/m120-verified):
//   A[m=lane&15][k=(lane>>4)*8+j]   B[k=(lane>>4)*8+j][n=lane&15]
//   C: col(n)=lane&15, row(m)=(lane>>4)*4+reg
// ---------------------------------------------------------------------------

typedef __attribute__((ext_vector_type(8))) short bf16x8;
typedef __attribute__((ext_vector_type(4))) float f32x4;
typedef __attribute__((ext_vector_type(2))) float f32x2;

#define BLOCK_THREADS  256      // 4 waves
#define GRID_BLOCKS    1024     // 4 blocks/CU nominal; grid-stride over groups
#define ROWS_PER_GROUP 256      // 64 rows per wave per group

__device__ __forceinline__ float lrelu(float a) {
    return fmaxf(a, 0.01f * a);     // exact leaky_relu(0.01)
}

__device__ __forceinline__ f32x2 lrelu2(f32x2 a) {
    return __builtin_elementwise_max(a, a * 0.01f);
}

__device__ __forceinline__ float softplus(float v) {
    return fmaxf(v, 0.0f) + log1pf(expf(-fabsf(v)));   // jax.nn.softplus
}

// two fp32 -> packed bf16x2 (hardware RNE), 1 VALU op.
__device__ __forceinline__ unsigned cvt_pk_bf16(float lo, float hi) {
    unsigned r;
    asm("v_cvt_pk_bf16_f32 %0, %1, %2" : "=v"(r) : "v"(lo), "v"(hi));
    return r;
}

// residual v - float(bf16_hi(v)), where pk holds the packed hi pair
__device__ __forceinline__ float lo_of(float v, unsigned pk, bool hi_half) {
    const float h = __uint_as_float(hi_half ? (pk & 0xFFFF0000u) : (pk << 16));
    return v - h;
}

__global__ __launch_bounds__(BLOCK_THREADS) void dln_mfma(
    const float* __restrict__ x,
    const float* __restrict__ W1,  const float* __restrict__ b1,
    const float* __restrict__ W2,  const float* __restrict__ b2,
    const float* __restrict__ WLd, const float* __restrict__ bLd,
    const float* __restrict__ WLo, const float* __restrict__ bLo,
    float* __restrict__ out, int ngroups)
{
    const int tid  = threadIdx.x;
    const int lane = tid & 63;
    const int wv   = tid >> 6;          // wave id 0..3
    const int quad = lane >> 4;         // 0..3
    const int c    = lane & 15;         // 0..15

    // ---- layer-1 A fragments: permuted W1 rows + b1 in k=4 slot, hi/lo ---
    bf16x8 a1hi[4], a1lo[4];
#pragma unroll
    for (int mt = 0; mt < 4; ++mt) {
        const int nu = 32 * (mt >> 1) + 8 * (c >> 2) + 4 * (mt & 1) + (c & 3);
        const float4 w = *(const float4*)(W1 + 4 * nu);   // W1 is (64,4) row-major
        const float bb = b1[nu];
        const unsigned h01 = cvt_pk_bf16(w.x, w.y);
        const unsigned h23 = cvt_pk_bf16(w.z, w.w);
        const unsigned hb  = cvt_pk_bf16(bb, 0.0f);
        const unsigned l01 = cvt_pk_bf16(lo_of(w.x, h01, false), lo_of(w.y, h01, true));
        const unsigned l23 = cvt_pk_bf16(lo_of(w.z, h23, false), lo_of(w.w, h23, true));
        const unsigned lb  = cvt_pk_bf16(lo_of(bb, hb, false), 0.0f);
        const uint4 z  = make_uint4(0u, 0u, 0u, 0u);
        const uint4 uh = (quad == 0) ? make_uint4(h01, h23, hb, 0u) : z;
        const uint4 ul = (quad == 0) ? make_uint4(l01, l23, lb, 0u) : z;
        a1hi[mt] = __builtin_bit_cast(bf16x8, uh);
        a1lo[mt] = __builtin_bit_cast(bf16x8, ul);
    }

    // ---- layer-2 A fragments (W2 bf16), head weights, biases -------------
    bf16x8 afrag[4][2];
    f32x4 wld0[4], wld1[4], wlo[4], b2v[4];
#pragma unroll
    for (int mt = 0; mt < 4; ++mt) {
        const float* wr = W2 + (16 * mt + c) * 64 + 8 * quad;
#pragma unroll
        for (int s = 0; s < 2; ++s) {
            const float4 f0 = *(const float4*)(wr + 32 * s);
            const float4 f1 = *(const float4*)(wr + 32 * s + 4);
            uint4 u;
            u.x = cvt_pk_bf16(f0.x, f0.y);
            u.y = cvt_pk_bf16(f0.z, f0.w);
            u.z = cvt_pk_bf16(f1.x, f1.y);
            u.w = cvt_pk_bf16(f1.z, f1.w);
            afrag[mt][s] = __builtin_bit_cast(bf16x8, u);
        }
        const int nb = 16 * mt + 4 * quad;   // this lane's 16 h2 neurons
        wld0[mt] = *(const f32x4*)(WLd + nb);
        wld1[mt] = *(const f32x4*)(WLd + 64 + nb);
        wlo[mt]  = *(const f32x4*)(WLo + nb);
        b2v[mt]  = *(const f32x4*)(b2 + nb);
    }
    const float bld0 = bLd[0];
    const float bld1 = bLd[1];
    const float blo0 = bLo[0];

    for (int grp = blockIdx.x; grp < ngroups; grp += gridDim.x) {
        const int wbase = grp * ROWS_PER_GROUP + wv * 64;   // this wave's 64 rows

        // all 4 row-tiles' x in flight early (rows wbase + it*16 + c)
        float4 xv[4];
#pragma unroll
        for (int it = 0; it < 4; ++it)
            xv[it] = ((const float4*)x)[wbase + it * 16 + c];

        float sld0 = 0.0f, sld1 = 0.0f, slo = 0.0f;
#pragma unroll
        for (int it = 0; it < 4; ++it) {
            // ---- layer-1 B fragment: x row it*16+c in k=0..3, 1.0 in k=4 -
            const unsigned xh01 = cvt_pk_bf16(xv[it].x, xv[it].y);
            const unsigned xh23 = cvt_pk_bf16(xv[it].z, xv[it].w);
            const unsigned xl01 = cvt_pk_bf16(lo_of(xv[it].x, xh01, false),
                                              lo_of(xv[it].y, xh01, true));
            const unsigned xl23 = cvt_pk_bf16(lo_of(xv[it].z, xh23, false),
                                              lo_of(xv[it].w, xh23, true));
            const uint4 z  = make_uint4(0u, 0u, 0u, 0u);
            const uint4 bh = (quad == 0) ? make_uint4(xh01, xh23, 0x00003F80u, 0u) : z;
            const uint4 bl = (quad == 0) ? make_uint4(xl01, xl23, 0u, 0u) : z;
            const bf16x8 bqh = __builtin_bit_cast(bf16x8, bh);
            const bf16x8 bql = __builtin_bit_cast(bf16x8, bl);

            // ---- layer-1 MFMA (hi*hi + hi*lo + lo*hi) --------------------
            f32x4 acc1[4];
#pragma unroll
            for (int mt = 0; mt < 4; ++mt) {
                f32x4 a = (f32x4){0.0f, 0.0f, 0.0f, 0.0f};
                a = __builtin_amdgcn_mfma_f32_16x16x32_bf16(a1hi[mt], bqh, a, 0, 0, 0);
                a = __builtin_amdgcn_mfma_f32_16x16x32_bf16(a1hi[mt], bql, a, 0, 0, 0);
                a = __builtin_amdgcn_mfma_f32_16x16x32_bf16(a1lo[mt], bqh, a, 0, 0, 0);
                acc1[mt] = a;
            }

            // ---- lrelu + pack: identity handoff to layer-2 B fragments ---
            uint4 u0, u1;
            u0.x = cvt_pk_bf16(lrelu(acc1[0][0]), lrelu(acc1[0][1]));
            u0.y = cvt_pk_bf16(lrelu(acc1[0][2]), lrelu(acc1[0][3]));
            u0.z = cvt_pk_bf16(lrelu(acc1[1][0]), lrelu(acc1[1][1]));
            u0.w = cvt_pk_bf16(lrelu(acc1[1][2]), lrelu(acc1[1][3]));
            u1.x = cvt_pk_bf16(lrelu(acc1[2][0]), lrelu(acc1[2][1]));
            u1.y = cvt_pk_bf16(lrelu(acc1[2][2]), lrelu(acc1[2][3]));
            u1.z = cvt_pk_bf16(lrelu(acc1[3][0]), lrelu(acc1[3][1]));
            u1.w = cvt_pk_bf16(lrelu(acc1[3][2]), lrelu(acc1[3][3]));
            const bf16x8 bf0 = __builtin_bit_cast(bf16x8, u0);
            const bf16x8 bf1 = __builtin_bit_cast(bf16x8, u1);

            // ---- layer-2 MFMA + heads in-register (pk math) --------------
            f32x2 pld0 = {0.0f, 0.0f}, pld1 = {0.0f, 0.0f}, plo = {0.0f, 0.0f};
#pragma unroll
            for (int mt = 0; mt < 4; ++mt) {
                f32x4 acc = b2v[mt];                // bias pre-load
                acc = __builtin_amdgcn_mfma_f32_16x16x32_bf16(afrag[mt][0], bf0, acc, 0, 0, 0);
                acc = __builtin_amdgcn_mfma_f32_16x16x32_bf16(afrag[mt][1], bf1, acc, 0, 0, 0);
                // acc[r] = pre-act h2[row it*16+c][neuron 16mt+4quad+r]
                const f32x2 hlo = lrelu2((f32x2){acc[0], acc[1]});
                const f32x2 hhi = lrelu2((f32x2){acc[2], acc[3]});
                pld0 = __builtin_elementwise_fma(hlo, (f32x2){wld0[mt][0], wld0[mt][1]}, pld0);
                pld0 = __builtin_elementwise_fma(hhi, (f32x2){wld0[mt][2], wld0[mt][3]}, pld0);
                pld1 = __builtin_elementwise_fma(hlo, (f32x2){wld1[mt][0], wld1[mt][1]}, pld1);
                pld1 = __builtin_elementwise_fma(hhi, (f32x2){wld1[mt][2], wld1[mt][3]}, pld1);
                plo  = __builtin_elementwise_fma(hlo, (f32x2){wlo[mt][0],  wlo[mt][1]},  plo);
                plo  = __builtin_elementwise_fma(hhi, (f32x2){wlo[mt][2],  wlo[mt][3]},  plo);
            }
            // horizontal add, then reduce over the 4 quads (disjoint neurons)
            float r0 = pld0[0] + pld0[1];
            float r1 = pld1[0] + pld1[1];
            float r2 = plo[0]  + plo[1];
            r0 += __shfl_xor(r0, 16); r0 += __shfl_xor(r0, 32);
            r1 += __shfl_xor(r1, 16); r1 += __shfl_xor(r1, 32);
            r2 += __shfl_xor(r2, 16); r2 += __shfl_xor(r2, 32);
            // lane(q,c) keeps iteration it==q -> its own row (= wbase+lane)
            if (it == quad) { sld0 = r0; sld1 = r1; slo = r2; }
        }

        // ---- epilogue: one row per lane, fully coalesced store -----------
        {
            const float ld0 = softplus(sld0 + bld0);
            const float ld1 = softplus(sld1 + bld1);
            const float lo  = slo + blo0;
            float4 o;
            o.x = fmaf(ld0, ld0, 1e-9f);                  // H00
            o.y = ld0 * lo;                               // H01
            o.z = o.y;                                    // H10
            o.w = fmaf(lo, lo, fmaf(ld1, ld1, 1e-9f));    // H11
            reinterpret_cast<float4*>(out)[wbase + lane] = o;
        }
    }
}

// ---- scalar fallback for tail rows (nrows % 256) --------------------------
__global__ __launch_bounds__(256) void dln_tail(
    const float* __restrict__ x,
    const float* __restrict__ W1,  const float* __restrict__ b1,
    const float* __restrict__ W2,  const float* __restrict__ b2,
    const float* __restrict__ WLd, const float* __restrict__ bLd,
    const float* __restrict__ WLo, const float* __restrict__ bLo,
    float* __restrict__ out, int row0, int nrows)
{
    const int row = row0 + blockIdx.x * 256 + threadIdx.x;
    if (row >= nrows) return;
    const float4 qv = reinterpret_cast<const float4*>(x)[row];
    float h1[64];
#pragma unroll
    for (int j = 0; j < 64; ++j) {
        float a = b1[j];
        a = fmaf(qv.x, W1[4 * j + 0], a);
        a = fmaf(qv.y, W1[4 * j + 1], a);
        a = fmaf(qv.z, W1[4 * j + 2], a);
        a = fmaf(qv.w, W1[4 * j + 3], a);
        h1[j] = lrelu(a);
    }
    float ld0 = bLd[0], ld1 = bLd[1], lo = bLo[0];
#pragma unroll 4
    for (int j = 0; j < 64; ++j) {
        float a0 = b2[j], a1 = 0.0f;
        const float* w = W2 + 64 * j;
#pragma unroll
        for (int k = 0; k < 64; k += 2) {
            a0 = fmaf(h1[k],     w[k],     a0);
            a1 = fmaf(h1[k + 1], w[k + 1], a1);
        }
        const float a = lrelu(a0 + a1);
        ld0 = fmaf(a, WLd[j],      ld0);
        ld1 = fmaf(a, WLd[64 + j], ld1);
        lo  = fmaf(a, WLo[j],      lo);
    }
    ld0 = softplus(ld0);
    ld1 = softplus(ld1);
    float4 o;
    o.x = fmaf(ld0, ld0, 1e-9f);
    o.y = ld0 * lo;
    o.z = o.y;
    o.w = fmaf(lo, lo, fmaf(ld1, ld1, 1e-9f));
    reinterpret_cast<float4*>(out)[row] = o;
}

extern "C" void kernel_launch(void* const* d_in, const int* in_sizes, int n_in,
                              void* d_out, int out_size, void* d_ws, size_t ws_size,
                              hipStream_t stream)
{
    const float* x   = (const float*)d_in[0];
    const float* W1  = (const float*)d_in[1];
    const float* b1  = (const float*)d_in[2];
    const float* W2  = (const float*)d_in[3];
    const float* b2  = (const float*)d_in[4];
    const float* WLd = (const float*)d_in[5];
    const float* bLd = (const float*)d_in[6];
    const float* WLo = (const float*)d_in[7];
    const float* bLo = (const float*)d_in[8];
    float* out = (float*)d_out;

    const int nrows   = in_sizes[0] / 4;            // x is (nrows, 4) fp32
    const int ngroups = nrows / ROWS_PER_GROUP;
    const int nfull   = ngroups * ROWS_PER_GROUP;
    const int rem     = nrows - nfull;

    if (ngroups > 0) {
        const int grid = (ngroups < GRID_BLOCKS) ? ngroups : GRID_BLOCKS;
        dln_mfma<<<grid, BLOCK_THREADS, 0, stream>>>(
            x, W1, b1, W2, b2, WLd, bLd, WLo, bLo, out, ngroups);
    }
    if (rem > 0)
        dln_tail<<<(rem + 255) / 256, 256, 0, stream>>>(
            x, W1, b1, W2, b2, WLd, bLd, WLo, bLo, out, nfull, nrows);
}